// Round 1
// baseline (1096.379 us; speedup 1.0000x reference)
//
#include <hip/hip_runtime.h>

#define B_ 512
#define D_ 512
#define L_ 32
#define H_ 300

__device__ __forceinline__ float bf2f(unsigned int hi16) {
    return __uint_as_float(hi16 << 16);
}
__device__ __forceinline__ unsigned short f2bf(float f) {
    unsigned int u = __float_as_uint(f);
    u += 0x7fffu + ((u >> 16) & 1u);   // round-to-nearest-even (inputs are finite)
    return (unsigned short)(u >> 16);
}

// ---------------- encoder: out = relu(in @ w + b), one block per row ----------------
template<int K, int N>
__global__ __launch_bounds__(256) void mlp_relu_kernel(const float* __restrict__ in,
        const float* __restrict__ w, const float* __restrict__ bias,
        float* __restrict__ out) {
    __shared__ float rs[K];
    int row = blockIdx.x;
    for (int k = threadIdx.x; k < K; k += 256) rs[k] = in[row * K + k];
    __syncthreads();
    for (int c = threadIdx.x; c < N; c += 256) {
        float acc = bias[c];
        #pragma unroll 4
        for (int k = 0; k < K; ++k) acc = fmaf(rs[k], w[k * N + c], acc);
        out[row * N + c] = fmaxf(acc, 0.f);
    }
}

// ---------------- latent heads: z_mean, z_log_var, z ----------------
__global__ __launch_bounds__(64) void latent_kernel(const float* __restrict__ h2,
        const float* __restrict__ eps,
        const float* __restrict__ zm_w, const float* __restrict__ zm_b,
        const float* __restrict__ zl_w, const float* __restrict__ zl_b,
        float* __restrict__ out, float* __restrict__ ws_z) {
    __shared__ float hs[H_];
    __shared__ float zm_s[L_], zl_s[L_];
    int row = blockIdx.x;
    int t = threadIdx.x;
    for (int k = t; k < H_; k += 64) hs[k] = h2[row * H_ + k];
    __syncthreads();
    {
        int l = t & 31;
        const float* wp = (t < 32) ? zm_w : zl_w;
        const float* bp = (t < 32) ? zm_b : zl_b;
        float acc = bp[l];
        #pragma unroll 4
        for (int k = 0; k < H_; ++k) acc = fmaf(hs[k], wp[k * L_ + l], acc);
        if (t < 32) zm_s[l] = acc; else zl_s[l] = acc;
    }
    __syncthreads();
    if (t < 32) {
        float zm = zm_s[t], zl = zl_s[t];
        float zv = zm + eps[row * L_ + t] * expf(0.5f * zl);
        float* z_out  = out + B_ * D_;
        float* zm_out = out + B_ * D_ + B_ * L_;
        float* zl_out = out + B_ * D_ + 2 * B_ * L_;
        z_out[row * L_ + t]  = zv;
        zm_out[row * L_ + t] = zm;
        zl_out[row * L_ + t] = zl;
        ws_z[row * L_ + t]   = zv;
    }
}

// ---------------- decoder: per (j, 64-batch tile) block ----------------
// masked = W[j]*z -> g1 = relu(masked @ gw1) (bf16 in LDS) ->
// g2 = relu(g1 @ gw2 + gb2) -> xrec[b] = sum_h g2*colw[j,h] + colb[j]
__global__ __launch_bounds__(256) void decode_kernel(
        const float* __restrict__ z, const float* __restrict__ Wmask,
        const float* __restrict__ gw1, const float* __restrict__ gw2,
        const float* __restrict__ gb2, const float* __restrict__ colw,
        const float* __restrict__ colb, float* __restrict__ xmean) {
    constexpr int BT = 64;      // batch rows per block
    constexpr int G1S = 302;    // g1 LDS row stride (bf16): stride%32 -> bank-conflict-free
    __shared__ float masked[BT][L_ + 1];
    __shared__ unsigned short g1s[BT * G1S];
    __shared__ float xrec[BT];

    int j  = blockIdx.y;
    int b0 = blockIdx.x * BT;
    int tid = threadIdx.x;

    if (tid < BT) xrec[tid] = 0.f;
    for (int i = tid; i < BT * L_; i += 256) {
        int b = i >> 5, l = i & 31;
        masked[b][l] = Wmask[j * L_ + l] * z[(b0 + b) * L_ + l];
    }
    __syncthreads();

    // ---- g1 phase: thread owns row b = tid>>2, quarter r = tid&3 of the 300 cols ----
    {
        int b = tid >> 2, r = tid & 3;
        float m[L_];
        #pragma unroll
        for (int l = 0; l < L_; ++l) m[l] = masked[b][l];
        for (int g = r; g < 75; g += 4) {          // 4 cols per iteration
            float4 acc = make_float4(0.f, 0.f, 0.f, 0.f);
            #pragma unroll
            for (int l = 0; l < L_; ++l) {
                float4 w4 = *reinterpret_cast<const float4*>(&gw1[l * H_ + 4 * g]);
                float mv = m[l];
                acc.x = fmaf(mv, w4.x, acc.x);
                acc.y = fmaf(mv, w4.y, acc.y);
                acc.z = fmaf(mv, w4.z, acc.z);
                acc.w = fmaf(mv, w4.w, acc.w);
            }
            int h = 4 * g;
            unsigned int p0 = (unsigned int)f2bf(fmaxf(acc.x, 0.f)) |
                              ((unsigned int)f2bf(fmaxf(acc.y, 0.f)) << 16);
            unsigned int p1 = (unsigned int)f2bf(fmaxf(acc.z, 0.f)) |
                              ((unsigned int)f2bf(fmaxf(acc.w, 0.f)) << 16);
            *reinterpret_cast<unsigned int*>(&g1s[b * G1S + h])     = p0;
            *reinterpret_cast<unsigned int*>(&g1s[b * G1S + h + 2]) = p1;
        }
    }
    __syncthreads();

    // ---- g2 + head: lane owns batch row b=lane; 8 h-columns register-blocked ----
    {
        int lane = tid & 63;
        int wv   = tid >> 6;
        float xacc = 0.f;
        for (int gg = wv; gg < 38; gg += 4) {
            int h0 = __builtin_amdgcn_readfirstlane(gg * 8);
            if (h0 + 8 <= H_) {
                float acc[8];
                #pragma unroll
                for (int u = 0; u < 8; ++u) acc[u] = 0.f;
                for (int k = 0; k < H_; k += 2) {
                    unsigned int pk = *reinterpret_cast<const unsigned int*>(&g1s[lane * G1S + k]);
                    float a0 = bf2f(pk & 0xffffu);
                    float a1 = bf2f(pk >> 16);
                    #pragma unroll
                    for (int u = 0; u < 8; ++u) {
                        acc[u] = fmaf(a0, gw2[k * H_ + h0 + u], acc[u]);
                        acc[u] = fmaf(a1, gw2[(k + 1) * H_ + h0 + u], acc[u]);
                    }
                }
                #pragma unroll
                for (int u = 0; u < 8; ++u)
                    xacc += fmaxf(acc[u] + gb2[h0 + u], 0.f) * colw[j * H_ + h0 + u];
            } else {                                   // tail: h0 = 296, 4 cols
                float acc[4];
                #pragma unroll
                for (int u = 0; u < 4; ++u) acc[u] = 0.f;
                for (int k = 0; k < H_; k += 2) {
                    unsigned int pk = *reinterpret_cast<const unsigned int*>(&g1s[lane * G1S + k]);
                    float a0 = bf2f(pk & 0xffffu);
                    float a1 = bf2f(pk >> 16);
                    #pragma unroll
                    for (int u = 0; u < 4; ++u) {
                        acc[u] = fmaf(a0, gw2[k * H_ + h0 + u], acc[u]);
                        acc[u] = fmaf(a1, gw2[(k + 1) * H_ + h0 + u], acc[u]);
                    }
                }
                #pragma unroll
                for (int u = 0; u < 4; ++u)
                    xacc += fmaxf(acc[u] + gb2[h0 + u], 0.f) * colw[j * H_ + h0 + u];
            }
        }
        atomicAdd(&xrec[lane], xacc);   // 4 waves -> 4 adds per row, distinct addr per lane
    }
    __syncthreads();

    if (tid < BT) {
        xmean[(size_t)(b0 + tid) * D_ + j] = xrec[tid] + colb[j];
    }
}

extern "C" void kernel_launch(void* const* d_in, const int* in_sizes, int n_in,
                              void* d_out, int out_size, void* d_ws, size_t ws_size,
                              hipStream_t stream) {
    const float* x     = (const float*)d_in[0];
    const float* eps   = (const float*)d_in[1];
    const float* Wm    = (const float*)d_in[2];
    const float* qz_w1 = (const float*)d_in[3];
    const float* qz_b1 = (const float*)d_in[4];
    const float* qz_w2 = (const float*)d_in[5];
    const float* qz_b2 = (const float*)d_in[6];
    const float* zm_w  = (const float*)d_in[7];
    const float* zm_b  = (const float*)d_in[8];
    const float* zl_w  = (const float*)d_in[9];
    const float* zl_b  = (const float*)d_in[10];
    const float* gw1   = (const float*)d_in[11];
    const float* gw2   = (const float*)d_in[12];
    const float* gb2   = (const float*)d_in[13];
    const float* colw  = (const float*)d_in[14];
    const float* colb  = (const float*)d_in[15];
    float* out = (float*)d_out;
    float* ws  = (float*)d_ws;

    float* h1 = ws;                  // 512*300
    float* h2 = ws + 153600;         // 512*300
    float* zb = ws + 307200;         // 512*32

    mlp_relu_kernel<512, 300><<<512, 256, 0, stream>>>(x,  qz_w1, qz_b1, h1);
    mlp_relu_kernel<300, 300><<<512, 256, 0, stream>>>(h1, qz_w2, qz_b2, h2);
    latent_kernel<<<512, 64, 0, stream>>>(h2, eps, zm_w, zm_b, zl_w, zl_b, out, zb);
    decode_kernel<<<dim3(8, 512), 256, 0, stream>>>(zb, Wm, gw1, gw2, gb2, colw, colb, out);
}

// Round 2
// 137.091 us; speedup vs baseline: 7.9974x; 7.9974x over previous
//
#include <hip/hip_runtime.h>

#define B_ 512
#define D_ 512
#define L_ 32
#define H_ 300
#define HP 304      // padded H (19*16)
#define NT 19       // 16-col n-tiles of H
#define NS 10       // 32-k steps of g2 (K=300 -> 320)
#define G1S 312     // g1 LDS row stride (ushorts): 16B-aligned, ~conflict-free
#define KSPLIT 0    // MFMA operand k-layout: 0 = 8 contiguous k per lane-group

typedef unsigned short ushort_t;
typedef __bf16 bf16x8 __attribute__((ext_vector_type(8)));
typedef float f32x4 __attribute__((ext_vector_type(4)));

__device__ __forceinline__ ushort_t f2bf(float f) {
    unsigned int u = __float_as_uint(f);
    u += 0x7fffu + ((u >> 16) & 1u);   // RNE (finite inputs)
    return (ushort_t)(u >> 16);
}
__device__ __forceinline__ int kbase0(int grp) { return KSPLIT ? 4 * grp : 8 * grp; }
__device__ __forceinline__ int kbase1(int grp) { return KSPLIT ? 16 + 4 * grp : 8 * grp + 4; }

// ---------------- encoder: out = relu(in @ w + b), one block per row ----------------
template<int K, int N>
__global__ __launch_bounds__(256) void mlp_relu_kernel(const float* __restrict__ in,
        const float* __restrict__ w, const float* __restrict__ bias,
        float* __restrict__ out) {
    __shared__ float rs[K];
    int row = blockIdx.x;
    for (int k = threadIdx.x; k < K; k += 256) rs[k] = in[row * K + k];
    __syncthreads();
    for (int c = threadIdx.x; c < N; c += 256) {
        float acc = bias[c];
        #pragma unroll 4
        for (int k = 0; k < K; ++k) acc = fmaf(rs[k], w[k * N + c], acc);
        out[row * N + c] = fmaxf(acc, 0.f);
    }
}

// ---------------- latent heads: z_mean, z_log_var, z ----------------
__global__ __launch_bounds__(64) void latent_kernel(const float* __restrict__ h2,
        const float* __restrict__ eps,
        const float* __restrict__ zm_w, const float* __restrict__ zm_b,
        const float* __restrict__ zl_w, const float* __restrict__ zl_b,
        float* __restrict__ out, float* __restrict__ ws_z) {
    __shared__ float hs[H_];
    __shared__ float zm_s[L_], zl_s[L_];
    int row = blockIdx.x;
    int t = threadIdx.x;
    for (int k = t; k < H_; k += 64) hs[k] = h2[row * H_ + k];
    __syncthreads();
    {
        int l = t & 31;
        const float* wp = (t < 32) ? zm_w : zl_w;
        const float* bp = (t < 32) ? zm_b : zl_b;
        float acc = bp[l];
        #pragma unroll 4
        for (int k = 0; k < H_; ++k) acc = fmaf(hs[k], wp[k * L_ + l], acc);
        if (t < 32) zm_s[l] = acc; else zl_s[l] = acc;
    }
    __syncthreads();
    if (t < 32) {
        float zm = zm_s[t], zl = zl_s[t];
        float zv = zm + eps[row * L_ + t] * expf(0.5f * zl);
        float* z_out  = out + B_ * D_;
        float* zm_out = out + B_ * D_ + B_ * L_;
        float* zl_out = out + B_ * D_ + 2 * B_ * L_;
        z_out[row * L_ + t]  = zv;
        zm_out[row * L_ + t] = zm;
        zl_out[row * L_ + t] = zl;
        ws_z[row * L_ + t]   = zv;
    }
}

// ------------- prep: swizzle gw1/gw2 (f32) into bf16 MFMA B-fragment layout -------------
// frag elem i of lane l = B[k][n], n = 16*nt + (l&15), k = ks + kbase(l>>4, i); pads -> 0
__global__ __launch_bounds__(64) void prep_kernel(const float* __restrict__ gw1,
        const float* __restrict__ gw2, ushort_t* __restrict__ gw1f,
        ushort_t* __restrict__ gw2f) {
    int blk = blockIdx.x;
    int l = threadIdx.x;
    int grp = l >> 4, li = l & 15;
    union { ushort_t u[8]; uint4 q; } V;
    if (blk < NT) {
        int nt = blk;
        int n = nt * 16 + li;
        #pragma unroll
        for (int i = 0; i < 8; ++i) {
            int k = (i < 4) ? kbase0(grp) + i : kbase1(grp) + (i - 4);
            V.u[i] = f2bf((n < H_) ? gw1[k * H_ + n] : 0.f);
        }
        *reinterpret_cast<uint4*>(gw1f + (nt * 64 + l) * 8) = V.q;
    } else {
        int idx = blk - NT;
        int nt = idx / NS, s = idx % NS;
        int n = nt * 16 + li;
        #pragma unroll
        for (int i = 0; i < 8; ++i) {
            int k = 32 * s + ((i < 4) ? kbase0(grp) + i : kbase1(grp) + (i - 4));
            V.u[i] = f2bf((k < H_ && n < H_) ? gw2[k * H_ + n] : 0.f);
        }
        *reinterpret_cast<uint4*>(gw2f + ((nt * NS + s) * 64 + l) * 8) = V.q;
    }
}

// ---------------- decoder: one block = (column j, 64 batch rows), MFMA ----------------
__global__ __launch_bounds__(256, 3) void decode_kernel(
        const float* __restrict__ z, const float* __restrict__ Wmask,
        const ushort_t* __restrict__ gw1f, const ushort_t* __restrict__ gw2f,
        const float* __restrict__ gb2, const float* __restrict__ colw,
        const float* __restrict__ colb, float* __restrict__ xmean) {
    __shared__ __align__(16) ushort_t mf[4 * 64 * 8];        // masked A-fragments (bf16)
    __shared__ __align__(16) ushort_t g1s[64 * G1S + 16];    // g1 bf16 [64][G1S] + tail pad
    __shared__ float xrec[64];

    const int j    = blockIdx.y;
    const int b0   = blockIdx.x * 64;
    const int tid  = threadIdx.x;
    const int w    = tid >> 6;
    const int lane = tid & 63;
    const int grp  = lane >> 4, li = lane & 15;

    // phase 0: build masked A-frags (masked = W[j]*z, bf16), zero pads
    {
        int b = b0 + w * 16 + li;                 // thread covers m-tile = w
        union { ushort_t u[8]; uint4 q; } V;
        #pragma unroll
        for (int i = 0; i < 8; ++i) {
            int k = (i < 4) ? kbase0(grp) + i : kbase1(grp) + (i - 4);
            V.u[i] = f2bf(Wmask[j * L_ + k] * z[b * L_ + k]);
        }
        *reinterpret_cast<uint4*>(&mf[(w * 64 + lane) * 8]) = V.q;
        if (tid < 64) xrec[tid] = 0.f;
        // zero unwritten g1 columns 304..311 (all rows) + 16-elem tail
        for (int idx = tid; idx < 64 * 8 + 16; idx += 256) {
            int r = idx >> 3, c = HP + (idx & 7);
            g1s[(idx < 512) ? (r * G1S + c) : (64 * G1S + (idx - 512))] = 0;
        }
    }
    __syncthreads();

    const int nlocal = (w == 3) ? 4 : 5;          // n-tiles 19 = 5+5+5+4 across waves

    // phase 1: g1 = relu(masked @ gw1)  [K=32, single MFMA step], bf16 -> LDS
    {
        bf16x8 am[4];
        #pragma unroll
        for (int mt = 0; mt < 4; ++mt)
            am[mt] = *reinterpret_cast<const bf16x8*>(&mf[(mt * 64 + lane) * 8]);
        #pragma unroll
        for (int ntl = 0; ntl < 5; ++ntl) {
            if (ntl < nlocal) {
                int nt = w * 5 + ntl;
                bf16x8 bfr = *reinterpret_cast<const bf16x8*>(gw1f + (nt * 64 + lane) * 8);
                int h = nt * 16 + li;
                #pragma unroll
                for (int mt = 0; mt < 4; ++mt) {
                    f32x4 c = {0.f, 0.f, 0.f, 0.f};
                    c = __builtin_amdgcn_mfma_f32_16x16x32_bf16(am[mt], bfr, c, 0, 0, 0);
                    #pragma unroll
                    for (int r = 0; r < 4; ++r) {
                        int m = mt * 16 + grp * 4 + r;       // C/D: row=4*grp+reg, col=li
                        g1s[m * G1S + h] = f2bf(fmaxf(c[r], 0.f));
                    }
                }
            }
        }
    }
    __syncthreads();

    // phase 2: g2 = relu(g1 @ gw2 + gb2), fused colw-dot epilogue
    {
        f32x4 acc[4][5];
        #pragma unroll
        for (int mt = 0; mt < 4; ++mt)
            #pragma unroll
            for (int n = 0; n < 5; ++n) acc[mt][n] = {0.f, 0.f, 0.f, 0.f};

        for (int s = 0; s < NS; ++s) {
            bf16x8 af[4];
            #pragma unroll
            for (int mt = 0; mt < 4; ++mt) {
                const ushort_t* p = &g1s[(mt * 16 + li) * G1S + 32 * s];
                union { bf16x8 v; uint2 d[2]; } U;
                U.d[0] = *reinterpret_cast<const uint2*>(p + kbase0(grp));
                U.d[1] = *reinterpret_cast<const uint2*>(p + kbase1(grp));
                af[mt] = U.v;
            }
            #pragma unroll
            for (int ntl = 0; ntl < 5; ++ntl) {
                if (ntl < nlocal) {
                    int nt = w * 5 + ntl;
                    bf16x8 bfr = *reinterpret_cast<const bf16x8*>(
                        gw2f + ((nt * NS + s) * 64 + lane) * 8);
                    #pragma unroll
                    for (int mt = 0; mt < 4; ++mt)
                        acc[mt][ntl] = __builtin_amdgcn_mfma_f32_16x16x32_bf16(
                            af[mt], bfr, acc[mt][ntl], 0, 0, 0);
                }
            }
        }

        // epilogue: relu(acc + gb2) * colw[j], reduce over h
        float partial[4][4] = {};
        #pragma unroll
        for (int ntl = 0; ntl < 5; ++ntl) {
            if (ntl < nlocal) {
                int h = (w * 5 + ntl) * 16 + li;
                float bias = 0.f, fac = 0.f;
                if (h < H_) { bias = gb2[h]; fac = colw[j * H_ + h]; }
                #pragma unroll
                for (int mt = 0; mt < 4; ++mt)
                    #pragma unroll
                    for (int r = 0; r < 4; ++r)
                        partial[mt][r] += fmaxf(acc[mt][ntl][r] + bias, 0.f) * fac;
            }
        }
        #pragma unroll
        for (int mt = 0; mt < 4; ++mt)
            #pragma unroll
            for (int r = 0; r < 4; ++r) {
                float v = partial[mt][r];
                v += __shfl_xor(v, 1);
                v += __shfl_xor(v, 2);
                v += __shfl_xor(v, 4);
                v += __shfl_xor(v, 8);
                if (li == 0) atomicAdd(&xrec[mt * 16 + grp * 4 + r], v);
            }
    }
    __syncthreads();

    if (tid < 64) xmean[(size_t)(b0 + tid) * D_ + j] = xrec[tid] + colb[j];
}

extern "C" void kernel_launch(void* const* d_in, const int* in_sizes, int n_in,
                              void* d_out, int out_size, void* d_ws, size_t ws_size,
                              hipStream_t stream) {
    const float* x     = (const float*)d_in[0];
    const float* eps   = (const float*)d_in[1];
    const float* Wm    = (const float*)d_in[2];
    const float* qz_w1 = (const float*)d_in[3];
    const float* qz_b1 = (const float*)d_in[4];
    const float* qz_w2 = (const float*)d_in[5];
    const float* qz_b2 = (const float*)d_in[6];
    const float* zm_w  = (const float*)d_in[7];
    const float* zm_b  = (const float*)d_in[8];
    const float* zl_w  = (const float*)d_in[9];
    const float* zl_b  = (const float*)d_in[10];
    const float* gw1   = (const float*)d_in[11];
    const float* gw2   = (const float*)d_in[12];
    const float* gb2   = (const float*)d_in[13];
    const float* colw  = (const float*)d_in[14];
    const float* colb  = (const float*)d_in[15];
    float* out = (float*)d_out;
    float* ws  = (float*)d_ws;

    float* h1 = ws;                  // 512*300 f32 (reused for frags after mlp2)
    float* h2 = ws + 153600;         // 512*300 f32
    float* zb = ws + 307200;         // 512*32  f32
    ushort_t* gw1f = (ushort_t*)ws;              // 19*64*8 bf16 (overlaps dead h1)
    ushort_t* gw2f = (ushort_t*)ws + 19 * 64 * 8;  // 19*10*64*8 bf16

    mlp_relu_kernel<512, 300><<<512, 256, 0, stream>>>(x,  qz_w1, qz_b1, h1);
    mlp_relu_kernel<300, 300><<<512, 256, 0, stream>>>(h1, qz_w2, qz_b2, h2);
    latent_kernel<<<512, 64, 0, stream>>>(h2, eps, zm_w, zm_b, zl_w, zl_b, out, zb);
    prep_kernel<<<NT + NT * NS, 64, 0, stream>>>(gw1, gw2, gw1f, gw2f);
    decode_kernel<<<dim3(8, 512), 256, 0, stream>>>(zb, Wm, gw1f, gw2f, gb2, colw, colb, out);
}